// Round 1
// baseline (418.376 us; speedup 1.0000x reference)
//
#include <hip/hip_runtime.h>
#include <cstdint>

#define BATCH 4
#define SLEN  4096
#define FDIM  64
#define KDIM  32

// ---------------------------------------------------------------------------
// Kernel 1: V = X @ W   (row-major X [B*S,64], W [64,64]) -> ws V [B*S,64]
// ---------------------------------------------------------------------------
__global__ __launch_bounds__(256) void xw_kernel(const float* __restrict__ X,
                                                 const float* __restrict__ W,
                                                 float* __restrict__ V) {
    int idx = blockIdx.x * 256 + threadIdx.x;   // [0, B*S*64)
    int o   = idx & 63;
    int row = idx >> 6;
    const float* __restrict__ xr = X + (size_t)row * FDIM;   // wave-uniform row
    float s0 = 0.f, s1 = 0.f, s2 = 0.f, s3 = 0.f;
#pragma unroll
    for (int f = 0; f < FDIM; f += 4) {
        s0 = fmaf(xr[f + 0], W[(f + 0) * FDIM + o], s0);
        s1 = fmaf(xr[f + 1], W[(f + 1) * FDIM + o], s1);
        s2 = fmaf(xr[f + 2], W[(f + 2) * FDIM + o], s2);
        s3 = fmaf(xr[f + 3], W[(f + 3) * FDIM + o], s3);
    }
    V[idx] = (s0 + s1) + (s2 + s3);
}

// ---------------------------------------------------------------------------
// Kernel 2: flash-style partials over a key chunk.
// One wave per block; lane = one query of a 64-query tile.
// No max-subtraction: p = exp(relu(s)) directly (max s ~72 < fp32 overflow).
// Partials are purely additive across key-splits.
// ---------------------------------------------------------------------------
__global__ __launch_bounds__(64) void attn_partial(const float* __restrict__ M,
                                                   const float* __restrict__ V,
                                                   float* __restrict__ accP,
                                                   float* __restrict__ lP,
                                                   int ksplit, int chunk) {
    const int qt   = blockIdx.x;
    const int b    = blockIdx.y;
    const int ks   = blockIdx.z;
    const int lane = threadIdx.x;
    const int q    = qt * 64 + lane;

    // Load this lane's query row (32 floats) into registers.
    const float* __restrict__ Mq = M + ((size_t)b * SLEN + q) * KDIM;
    float Q[KDIM];
#pragma unroll
    for (int k = 0; k < KDIM; k += 4) {
        float4 t = *reinterpret_cast<const float4*>(Mq + k);
        Q[k] = t.x; Q[k + 1] = t.y; Q[k + 2] = t.z; Q[k + 3] = t.w;
    }

    float acc[FDIM];
#pragma unroll
    for (int f = 0; f < FDIM; ++f) acc[f] = 0.f;
    float l = 0.f;

    const float* __restrict__ Mb = M + (size_t)b * SLEN * KDIM;
    const float* __restrict__ Vb = V + (size_t)b * SLEN * FDIM;

    const int j0 = ks * chunk;
    const int j1 = (j0 + chunk < SLEN) ? (j0 + chunk) : SLEN;

    for (int j = j0; j < j1; ++j) {
        // Key row: wave-uniform address -> scalar (s_load) broadcast expected.
        const float4* __restrict__ kp =
            reinterpret_cast<const float4*>(Mb + (size_t)j * KDIM);
        float s0 = 0.f, s1 = 0.f, s2 = 0.f, s3 = 0.f;
#pragma unroll
        for (int k4 = 0; k4 < KDIM / 4; ++k4) {
            float4 kv = kp[k4];
            s0 = fmaf(Q[4 * k4 + 0], kv.x, s0);
            s1 = fmaf(Q[4 * k4 + 1], kv.y, s1);
            s2 = fmaf(Q[4 * k4 + 2], kv.z, s2);
            s3 = fmaf(Q[4 * k4 + 3], kv.w, s3);
        }
        float s = (s0 + s1) + (s2 + s3);
        float p = __expf(fmaxf(s, 0.f));   // exp(relu(s)); exp(0)=1 for s<=0
        l += p;

        // Value row (wave-uniform address).
        const float4* __restrict__ vp =
            reinterpret_cast<const float4*>(Vb + (size_t)j * FDIM);
#pragma unroll
        for (int f4 = 0; f4 < FDIM / 4; ++f4) {
            float4 vv = vp[f4];
            acc[4 * f4 + 0] = fmaf(p, vv.x, acc[4 * f4 + 0]);
            acc[4 * f4 + 1] = fmaf(p, vv.y, acc[4 * f4 + 1]);
            acc[4 * f4 + 2] = fmaf(p, vv.z, acc[4 * f4 + 2]);
            acc[4 * f4 + 3] = fmaf(p, vv.w, acc[4 * f4 + 3]);
        }
    }

    const size_t pbase = ((size_t)b * SLEN + q) * (size_t)ksplit + ks;
    float4* __restrict__ ap = reinterpret_cast<float4*>(accP + pbase * FDIM);
#pragma unroll
    for (int f4 = 0; f4 < FDIM / 4; ++f4) {
        ap[f4] = make_float4(acc[4 * f4 + 0], acc[4 * f4 + 1],
                             acc[4 * f4 + 2], acc[4 * f4 + 3]);
    }
    lP[pbase] = l;
}

// ---------------------------------------------------------------------------
// Kernel 3: combine partials: out = V + (sum acc_i)/(sum l_i) + bias
// ---------------------------------------------------------------------------
__global__ __launch_bounds__(256) void combine_kernel(const float* __restrict__ V,
                                                      const float* __restrict__ accP,
                                                      const float* __restrict__ lP,
                                                      const float* __restrict__ bias,
                                                      float* __restrict__ out,
                                                      int ksplit) {
    int idx = blockIdx.x * 256 + threadIdx.x;   // [0, B*S*64)
    int o   = idx & 63;
    int row = idx >> 6;                          // b*S + q (wave-uniform)
    float num = 0.f, den = 0.f;
    for (int i = 0; i < ksplit; ++i) {
        num += accP[((size_t)row * ksplit + i) * FDIM + o];
        den += lP[(size_t)row * ksplit + i];     // wave-uniform -> s_load
    }
    out[idx] = V[idx] + num / den + bias[o];
}

// ---------------------------------------------------------------------------
extern "C" void kernel_launch(void* const* d_in, const int* in_sizes, int n_in,
                              void* d_out, int out_size, void* d_ws, size_t ws_size,
                              hipStream_t stream) {
    const float* X    = (const float*)d_in[0];   // [4,4096,64]
    const float* M    = (const float*)d_in[1];   // [4,4096,32]
    const float* W    = (const float*)d_in[2];   // [64,64]
    const float* bias = (const float*)d_in[3];   // [64]
    float* out = (float*)d_out;                  // [4,4096,64]

    const size_t vElems = (size_t)BATCH * SLEN * FDIM;   // 1,048,576

    // Pick largest key-split whose partial buffers fit in ws.
    int ksplit = 8;
    while (ksplit > 1) {
        size_t need = (vElems                       // V
                       + vElems * (size_t)ksplit    // accP
                       + (size_t)BATCH * SLEN * ksplit) // lP
                      * sizeof(float);
        if (need <= ws_size) break;
        ksplit >>= 1;
    }

    float* V    = (float*)d_ws;
    float* accP = V + vElems;
    float* lP   = accP + vElems * (size_t)ksplit;
    const int chunk = (SLEN + ksplit - 1) / ksplit;

    xw_kernel<<<(int)(vElems / 256), 256, 0, stream>>>(X, W, V);

    dim3 g2(SLEN / 64, BATCH, ksplit);
    attn_partial<<<g2, 64, 0, stream>>>(M, V, accP, lP, ksplit, chunk);

    combine_kernel<<<(int)(vElems / 256), 256, 0, stream>>>(V, accP, lP, bias,
                                                            out, ksplit);
}